// Round 19
// baseline (83.857 us; speedup 1.0000x reference)
//
#include <hip/hip_runtime.h>
#include <hip/hip_bf16.h>

#define NB 4
#define NN 4096
#define MM 4096
#define DD 128
#define BN 32
#define BM 64
#define NCH 8   // m-chunks; grid = 128*8 = 1024 blocks = 4/CU, XCD = wg&7 exactly
#define OUT_ELEMS ((size_t)NB * NN * DD)

using f32x4  = __attribute__((ext_vector_type(4))) float;
using bf16x8 = __attribute__((ext_vector_type(8))) short;

__device__ __forceinline__ float fast_exp2(float x) {
  return __builtin_amdgcn_exp2f(x);   // v_exp_f32: D = 2^S0
}

__device__ __forceinline__ int rfl(int x) {  // force wave-uniform -> SGPR
  return __builtin_amdgcn_readfirstlane(x);
}

__device__ __forceinline__ short f2bf(float x) {
  union { __hip_bfloat16 h; short s; } u;
  u.h = __float2bfloat16(x);
  return u.s;
}

__device__ __forceinline__ float bf2f(unsigned short s) {
  union { float f; unsigned u; } u;
  u.u = ((unsigned)s) << 16;
  return u.f;
}

__device__ __forceinline__ bf16x8 pack8(const float* __restrict__ p) {
  float4 a = *(const float4*)p;
  float4 b = *(const float4*)(p + 4);
  bf16x8 r;
  r[0] = f2bf(a.x); r[1] = f2bf(a.y); r[2] = f2bf(a.z); r[3] = f2bf(a.w);
  r[4] = f2bf(b.x); r[5] = f2bf(b.y); r[6] = f2bf(b.z); r[7] = f2bf(b.w);
  return r;
}

__global__ __launch_bounds__(256) void zero_out_kernel(float4* __restrict__ out) {
  out[(size_t)blockIdx.x * 256 + threadIdx.x] = (float4){0.f, 0.f, 0.f, 0.f};
}

// Fused prep: y=0 -> Q frag-tiled, y=1 -> V transpose+frag. (K stays fp32:
// each block reads its 32 K-rows once in the prologue — no round-trip needed.)
__global__ __launch_bounds__(256) void prep_kernel(
    const float* __restrict__ q, const float* __restrict__ v,
    unsigned short* __restrict__ qbt, unsigned short* __restrict__ vtt) {
  __shared__ unsigned short t[64][72];   // used by the V-transpose branch only
  if (blockIdx.y == 0) {
    const int blk = blockIdx.x;          // b*256 + rf
    const int b = blk >> 8, rf = blk & 255;
    const int kf = threadIdx.x >> 6, l = threadIdx.x & 63;
    const int lr = l & 15, hg = l >> 4;
    const float* s = q + ((size_t)(b * 4096 + rf * 16 + lr) * DD + kf * 32 + hg * 8);
    *(bf16x8*)(qbt + (((size_t)((b * 256 + rf) * 4 + kf)) << 9) + (l << 3)) = pack8(s);
    return;
  }
  if (blockIdx.x >= 512) return;         // V branch needs 512 of the 1024 blocks
  const int b = blockIdx.x >> 7;
  const int rem = blockIdx.x & 127;
  const int d0 = (rem >> 6) * 64, m0 = (rem & 63) * 64;
  const int r = threadIdx.x >> 2, c4 = threadIdx.x & 3;
  const float* src = v + ((size_t)b * MM + m0 + r) * DD + d0 + c4 * 16;
  for (int j = 0; j < 4; ++j) {
    float4 x = *(const float4*)(src + j * 4);
    int dl = c4 * 16 + j * 4;
    t[dl + 0][r] = (unsigned short)f2bf(x.x);
    t[dl + 1][r] = (unsigned short)f2bf(x.y);
    t[dl + 2][r] = (unsigned short)f2bf(x.z);
    t[dl + 3][r] = (unsigned short)f2bf(x.w);
  }
  __syncthreads();
  const int s8 = threadIdx.x >> 5;          // 0..7 sub-tiles (16d x 32m)
  const int dfl = s8 & 3, mtl = s8 >> 2;
  const int t32 = threadIdx.x & 31;
  for (int ll = 0; ll < 2; ++ll) {
    const int l = t32 * 2 + ll;
    const int lr = l & 15, hg = l >> 4;
    bf16x8 val = *(bf16x8*)&t[dfl * 16 + lr][mtl * 32 + hg * 8];
    *(bf16x8*)(vtt + (((size_t)((b * 8 + (d0 >> 4) + dfl) * 128 + (m0 >> 5) + mtl)) << 9) +
               (l << 3)) = val;
  }
}

// Sum NCH fragment-ordered bf16 partials -> f32 out[b][n][d]
__global__ __launch_bounds__(256) void reduce8_frag_kernel(const unsigned short* __restrict__ p,
                                                           float* __restrict__ out) {
  const size_t idx = (size_t)blockIdx.x * 256 + threadIdx.x;  // 524288 total
  float r0 = 0.f, r1 = 0.f, r2 = 0.f, r3 = 0.f;
  for (int c = 0; c < NCH; ++c) {
    ushort4 a = *(const ushort4*)(p + (size_t)c * OUT_ELEMS + idx * 4);
    r0 += bf2f(a.x); r1 += bf2f(a.y); r2 += bf2f(a.z); r3 += bf2f(a.w);
  }
  const int l = (int)(idx & 63);
  const int djg = (int)((idx >> 6) & 7);
  const int nf = (int)((idx >> 9) & 255);
  const int bq = (int)(idx >> 17);
  const int lr = l & 15, hg = l >> 4;
  float* o = out + ((size_t)(bq * 4096 + nf * 16 + hg * 4) * DD + djg * 16 + lr);
  o[0] = r0; o[DD] = r1; o[2 * DD] = r2; o[3 * DD] = r3;
}

// Raw barrier: LDS visibility only — global loads stay in flight (no vmcnt drain).
#define LGKM0_SBAR()                                        \
  do {                                                      \
    asm volatile("s_waitcnt lgkmcnt(0)" ::: "memory");      \
    __builtin_amdgcn_sched_barrier(0);                      \
    __builtin_amdgcn_s_barrier();                           \
  } while (0)

// Fused main kernel — R14 structure (proven 62.2 us): NCH=8 (4 blocks/CU),
// fragment-tiled Q/V operands (SGPR base + lane*16B), K direct from fp32 in
// prologue, QK transposed, bf16 S-exchange, b64 W writes w/ XOR swizzle, 32 KB LDS.
template <bool WS, bool PART>
__global__ __launch_bounds__(512, 4) void attn_fused(
    const float* __restrict__ k, const float* __restrict__ q, const float* __restrict__ v,
    const unsigned short* __restrict__ qbt, const unsigned short* __restrict__ vtt,
    void* __restrict__ outp) {
  __shared__ alignas(8)  unsigned short s_pos[NB][8][64][4];   // 16 KB bf16 S^T exchange
  __shared__ alignas(16) unsigned short Wl[NB][BN][BM];        // 16 KB [b][n][m], m swizzled

  const int tid = threadIdx.x;
  const int wv = tid >> 6, l = tid & 63, lr = l & 15, hg = l >> 4;
  const int voff = l << 3;                  // lane offset in elems (16 B)
  const int wg = blockIdx.x;
  const int cid = wg & (NCH - 1);           // == XCD id
  const int nt = wg >> 3;                   // n-tile 0..127
  const int n0 = nt * BN;
  const int it0 = cid * (MM / BM / NCH);
  const int it1 = it0 + (MM / BM / NCH);

  const int bq = wv >> 1, h = wv & 1;          // (batch, m-half) for QK/PV phases
  const int h_s = wv >> 2, fi_s = (wv >> 1) & 1, fj_s = wv & 1;  // softmax slot

  // K fragments (register-cached, loaded once from fp32): rows n0..n0+31, batch bq
  bf16x8 ka[2][4];
  for (int fn = 0; fn < 2; ++fn)
    for (int kf = 0; kf < 4; ++kf)
      ka[fn][kf] = pack8(k + ((size_t)bq * NN + n0 + fn * 16 + lr) * DD + kf * 32 + hg * 8);

  f32x4 acc[2][4];
  for (int fi = 0; fi < 2; ++fi)
    for (int dj = 0; dj < 4; ++dj) acc[fi][dj] = (f32x4){0.f, 0.f, 0.f, 0.f};

  bf16x8 vf[4][2];   // V fragments, live across one barrier
  bf16x8 qf[2][4];   // Q fragments

  auto load_q = [&](int it) {
    if (WS) {
      const unsigned short* qp = qbt + rfl(((bq * 256 + it * 4 + h * 2) * 4) << 9);
      for (int fm = 0; fm < 2; ++fm)
        for (int kf = 0; kf < 4; ++kf)
          qf[fm][kf] = *(const bf16x8*)(qp + fm * 2048 + kf * 512 + voff);
    } else {
      const int m0 = it * BM;
      for (int fm = 0; fm < 2; ++fm)
        for (int kf = 0; kf < 4; ++kf)
          qf[fm][kf] = pack8(q + ((size_t)bq * MM + m0 + h * 32 + fm * 16 + lr) * DD +
                             kf * 32 + hg * 8);
    }
  };

  auto qk_mfma = [&]() {
    f32x4 s[2][2];   // [fm][fn], S^T: row=m, col=n
    for (int fm = 0; fm < 2; ++fm)
      for (int fn = 0; fn < 2; ++fn) s[fm][fn] = (f32x4){0.f, 0.f, 0.f, 0.f};
    __builtin_amdgcn_s_setprio(1);
    for (int kf = 0; kf < 4; ++kf)
      for (int fm = 0; fm < 2; ++fm)
        for (int fn = 0; fn < 2; ++fn)
          s[fm][fn] = __builtin_amdgcn_mfma_f32_16x16x32_bf16(qf[fm][kf], ka[fn][kf],
                                                              s[fm][fn], 0, 0, 0);
    __builtin_amdgcn_s_setprio(0);
    for (int fm = 0; fm < 2; ++fm)
      for (int fn = 0; fn < 2; ++fn) {
        short4 pk;
        pk.x = f2bf(s[fm][fn][0]); pk.y = f2bf(s[fm][fn][1]);
        pk.z = f2bf(s[fm][fn][2]); pk.w = f2bf(s[fm][fn][3]);
        *(short4*)&s_pos[bq][h * 4 + fm * 2 + fn][l][0] = pk;   // b64
      }
  };

  auto issue_v = [&](int it) {
    if (WS) {
      const unsigned short* vp = vtt + rfl((((bq * 8 + h * 4) * 128) + it * 2) << 9);
      for (int dj = 0; dj < 4; ++dj)
        for (int kf = 0; kf < 2; ++kf)
          vf[dj][kf] = *(const bf16x8*)(vp + dj * 65536 + kf * 512 + voff);
    } else {
      const int m0 = it * BM;
      for (int dj = 0; dj < 4; ++dj)
        for (int kf = 0; kf < 2; ++kf) {
          bf16x8 t;
          for (int e = 0; e < 8; ++e)
            t[e] = f2bf(v[((size_t)bq * MM + m0 + kf * 32 + hg * 8 + e) * DD +
                          h * 64 + dj * 16 + lr]);
          vf[dj][kf] = t;
        }
    }
  };

  auto do_sm = [&]() {
    // slot wv: m = h_s*32 + fi_s*16 + hg*4 + qq (4 consecutive), n = fj_s*16 + lr
    float sv[NB][4], w[NB][4];
    for (int bb = 0; bb < NB; ++bb) {
      short4 sp = *(short4*)&s_pos[bb][wv][l][0];
      sv[bb][0] = bf2f((unsigned short)sp.x); sv[bb][1] = bf2f((unsigned short)sp.y);
      sv[bb][2] = bf2f((unsigned short)sp.z); sv[bb][3] = bf2f((unsigned short)sp.w);
    }
    const float L2E = 1.4426950408889634f;
    for (int qq = 0; qq < 4; ++qq) {
      float e0 = fast_exp2(sv[0][qq] * L2E), e1 = fast_exp2(sv[1][qq] * L2E);
      float e2 = fast_exp2(sv[2][qq] * L2E), e3 = fast_exp2(sv[3][qq] * L2E);
      float inv = __builtin_amdgcn_rcpf((e0 + e1) + (e2 + e3)) * L2E;
      float f0 = fast_exp2(e0 * inv), f1 = fast_exp2(e1 * inv);
      float f2v = fast_exp2(e2 * inv), f3 = fast_exp2(e3 * inv);
      float inv2 = __builtin_amdgcn_rcpf((f0 + f1) + (f2v + f3));
      w[0][qq] = f0 * inv2; w[1][qq] = f1 * inv2;
      w[2][qq] = f2v * inv2; w[3][qq] = f3 * inv2;
    }
    const int n_loc = fj_s * 16 + lr;
    const int mchunk = (h_s * 4 + fi_s * 2 + (hg >> 1)) ^ (n_loc & 7);
    const int moff = mchunk * 8 + (hg & 1) * 4;
    for (int bb = 0; bb < NB; ++bb) {
      short4 pk;
      pk.x = f2bf(w[bb][0]); pk.y = f2bf(w[bb][1]);
      pk.z = f2bf(w[bb][2]); pk.w = f2bf(w[bb][3]);
      *(short4*)&Wl[bb][n_loc][moff] = pk;   // b64, 4 consecutive m
    }
  };

  auto do_pv = [&]() {
    bf16x8 wf[2][2];
    for (int fi = 0; fi < 2; ++fi)
      for (int kf = 0; kf < 2; ++kf) {
        const int row = fi * 16 + lr, mo = kf * 32 + hg * 8;
        wf[fi][kf] = *(bf16x8*)&Wl[bq][row][mo ^ ((row & 7) << 3)];
      }
    __builtin_amdgcn_s_setprio(1);
    for (int kf = 0; kf < 2; ++kf)
      for (int fi = 0; fi < 2; ++fi)
        for (int dj = 0; dj < 4; ++dj)
          acc[fi][dj] = __builtin_amdgcn_mfma_f32_16x16x32_bf16(wf[fi][kf], vf[dj][kf],
                                                                acc[fi][dj], 0, 0, 0);
    __builtin_amdgcn_s_setprio(0);
  };

  // ---- rotated pipeline, 2 raw barriers per iteration (R9/R14-proven order) ----
  load_q(it0);
  qk_mfma();
  LGKM0_SBAR();
  for (int t = it0; t < it1; ++t) {
    issue_v(t);              // V loads in flight across the barrier, land before PV
    do_sm();
    LGKM0_SBAR();
    do_pv();                 // vf dies here; load_q after keeps peak liveness low
    if (t + 1 < it1) {
      load_q(t + 1);
      qk_mfma();
    }
    LGKM0_SBAR();
  }

  // ---- epilogue ----
  if (PART) {
    unsigned short* dst = (unsigned short*)outp + (size_t)cid * OUT_ELEMS +
                          rfl((((bq * 256 + nt * 2) * 8 + h * 4)) << 8);
    for (int fi = 0; fi < 2; ++fi)
      for (int dj = 0; dj < 4; ++dj) {
        short4 pk;
        pk.x = f2bf(acc[fi][dj][0]); pk.y = f2bf(acc[fi][dj][1]);
        pk.z = f2bf(acc[fi][dj][2]); pk.w = f2bf(acc[fi][dj][3]);
        *(short4*)(dst + fi * 2048 + dj * 256 + (l << 2)) = pk;
      }
  } else {
    float* dst = (float*)outp;
    for (int fi = 0; fi < 2; ++fi)
      for (int dj = 0; dj < 4; ++dj)
        for (int qq = 0; qq < 4; ++qq)
          atomicAdd(dst + ((size_t)bq * NN + n0 + fi * 16 + hg * 4 + qq) * DD +
                        h * 64 + dj * 16 + lr,
                    acc[fi][dj][qq]);
  }
}

extern "C" void kernel_launch(void* const* d_in, const int* in_sizes, int n_in,
                              void* d_out, int out_size, void* d_ws, size_t ws_size,
                              hipStream_t stream) {
  (void)in_sizes; (void)n_in; (void)out_size;
  const float* k = (const float*)d_in[0];
  const float* q = (const float*)d_in[1];
  const float* v = (const float*)d_in[2];
  float* out = (float*)d_out;

  const size_t elems = (size_t)NB * MM * DD;                    // 2M per tensor
  const size_t need_bf = 2 * elems * sizeof(unsigned short);    // qbt + vtt = 8 MB
  const size_t need_full = need_bf + NCH * OUT_ELEMS * sizeof(unsigned short);  // 40 MB
  const bool use_ws = (d_ws != nullptr) && (ws_size >= need_bf);
  const bool use_part = (d_ws != nullptr) && (ws_size >= need_full);

  if (use_ws) {
    unsigned short* qbt = (unsigned short*)d_ws;
    unsigned short* vtt = qbt + elems;
    prep_kernel<<<dim3(NB * 256, 2), 256, 0, stream>>>(q, v, qbt, vtt);
    if (use_part) {
      unsigned short* partials = vtt + elems;
      attn_fused<true, true><<<dim3(NN / BN * NCH), 512, 0, stream>>>(k, q, v, qbt, vtt,
                                                                      (void*)partials);
      reduce8_frag_kernel<<<2048, 256, 0, stream>>>(partials, out);
    } else {
      zero_out_kernel<<<(NB * NN * DD) / 4 / 256, 256, 0, stream>>>((float4*)out);
      attn_fused<true, false><<<dim3(NN / BN * NCH), 512, 0, stream>>>(k, q, v, qbt, vtt,
                                                                       (void*)out);
    }
  } else {
    zero_out_kernel<<<(NB * NN * DD) / 4 / 256, 256, 0, stream>>>((float4*)out);
    attn_fused<false, false><<<dim3(NN / BN * NCH), 512, 0, stream>>>(k, q, v, nullptr,
                                                                      nullptr, (void*)out);
  }
}

// Round 20
// 76.993 us; speedup vs baseline: 1.0891x; 1.0891x over previous
//
#include <hip/hip_runtime.h>
#include <hip/hip_bf16.h>

#define NB 4
#define NN 4096
#define MM 4096
#define DD 128
#define BN 32
#define BM 64
#define NCH 8   // m-chunks; grid = 128*8 = 1024 blocks = 4/CU, XCD = wg&7 exactly
#define OUT_ELEMS ((size_t)NB * NN * DD)

using f32x4  = __attribute__((ext_vector_type(4))) float;
using bf16x8 = __attribute__((ext_vector_type(8))) short;

__device__ __forceinline__ float fast_exp2(float x) {
  return __builtin_amdgcn_exp2f(x);   // v_exp_f32: D = 2^S0
}

__device__ __forceinline__ int rfl(int x) {  // force wave-uniform -> SGPR
  return __builtin_amdgcn_readfirstlane(x);
}

__device__ __forceinline__ short f2bf(float x) {
  union { __hip_bfloat16 h; short s; } u;
  u.h = __float2bfloat16(x);
  return u.s;
}

__device__ __forceinline__ float bf2f(unsigned short s) {
  union { float f; unsigned u; } u;
  u.u = ((unsigned)s) << 16;
  return u.f;
}

__device__ __forceinline__ bf16x8 pack8(const float* __restrict__ p) {
  float4 a = *(const float4*)p;
  float4 b = *(const float4*)(p + 4);
  bf16x8 r;
  r[0] = f2bf(a.x); r[1] = f2bf(a.y); r[2] = f2bf(a.z); r[3] = f2bf(a.w);
  r[4] = f2bf(b.x); r[5] = f2bf(b.y); r[6] = f2bf(b.z); r[7] = f2bf(b.w);
  return r;
}

__global__ __launch_bounds__(256) void zero_out_kernel(float4* __restrict__ out) {
  out[(size_t)blockIdx.x * 256 + threadIdx.x] = (float4){0.f, 0.f, 0.f, 0.f};
}

// Fused prep: y=0 -> K frag-tiled, y=1 -> Q frag-tiled, y=2 -> V transpose+frag.
__global__ __launch_bounds__(256) void prep_kernel(
    const float* __restrict__ k, const float* __restrict__ q, const float* __restrict__ v,
    unsigned short* __restrict__ kbt, unsigned short* __restrict__ qbt,
    unsigned short* __restrict__ vtt) {
  __shared__ unsigned short t[64][72];   // used by the V-transpose branch only
  if (blockIdx.y < 2) {
    const float* src = blockIdx.y ? q : k;
    unsigned short* dst = blockIdx.y ? qbt : kbt;
    const int blk = blockIdx.x;          // b*256 + rf
    const int b = blk >> 8, rf = blk & 255;
    const int kf = threadIdx.x >> 6, l = threadIdx.x & 63;
    const int lr = l & 15, hg = l >> 4;
    const float* s = src + ((size_t)(b * 4096 + rf * 16 + lr) * DD + kf * 32 + hg * 8);
    *(bf16x8*)(dst + (((size_t)((b * 256 + rf) * 4 + kf)) << 9) + (l << 3)) = pack8(s);
    return;
  }
  if (blockIdx.x >= 512) return;         // V branch needs 512 of the 1024 blocks
  const int b = blockIdx.x >> 7;
  const int rem = blockIdx.x & 127;
  const int d0 = (rem >> 6) * 64, m0 = (rem & 63) * 64;
  const int r = threadIdx.x >> 2, c4 = threadIdx.x & 3;
  const float* src = v + ((size_t)b * MM + m0 + r) * DD + d0 + c4 * 16;
  for (int j = 0; j < 4; ++j) {
    float4 x = *(const float4*)(src + j * 4);
    int dl = c4 * 16 + j * 4;
    t[dl + 0][r] = (unsigned short)f2bf(x.x);
    t[dl + 1][r] = (unsigned short)f2bf(x.y);
    t[dl + 2][r] = (unsigned short)f2bf(x.z);
    t[dl + 3][r] = (unsigned short)f2bf(x.w);
  }
  __syncthreads();
  const int s8 = threadIdx.x >> 5;          // 0..7 sub-tiles (16d x 32m)
  const int dfl = s8 & 3, mtl = s8 >> 2;
  const int t32 = threadIdx.x & 31;
  for (int ll = 0; ll < 2; ++ll) {
    const int l = t32 * 2 + ll;
    const int lr = l & 15, hg = l >> 4;
    bf16x8 val = *(bf16x8*)&t[dfl * 16 + lr][mtl * 32 + hg * 8];
    *(bf16x8*)(vtt + (((size_t)((b * 8 + (d0 >> 4) + dfl) * 128 + (m0 >> 5) + mtl)) << 9) +
               (l << 3)) = val;
  }
}

// Sum NCH fragment-ordered bf16 partials -> f32 out[b][n][d]
__global__ __launch_bounds__(256) void reduce8_frag_kernel(const unsigned short* __restrict__ p,
                                                           float* __restrict__ out) {
  const size_t idx = (size_t)blockIdx.x * 256 + threadIdx.x;  // 524288 total
  float r0 = 0.f, r1 = 0.f, r2 = 0.f, r3 = 0.f;
  for (int c = 0; c < NCH; ++c) {
    ushort4 a = *(const ushort4*)(p + (size_t)c * OUT_ELEMS + idx * 4);
    r0 += bf2f(a.x); r1 += bf2f(a.y); r2 += bf2f(a.z); r3 += bf2f(a.w);
  }
  const int l = (int)(idx & 63);
  const int djg = (int)((idx >> 6) & 7);
  const int nf = (int)((idx >> 9) & 255);
  const int bq = (int)(idx >> 17);
  const int lr = l & 15, hg = l >> 4;
  float* o = out + ((size_t)(bq * 4096 + nf * 16 + hg * 4) * DD + djg * 16 + lr);
  o[0] = r0; o[DD] = r1; o[2 * DD] = r2; o[3 * DD] = r3;
}

// Raw barrier: LDS visibility only — global loads stay in flight (no vmcnt drain).
#define LGKM0_SBAR()                                        \
  do {                                                      \
    asm volatile("s_waitcnt lgkmcnt(0)" ::: "memory");      \
    __builtin_amdgcn_sched_barrier(0);                      \
    __builtin_amdgcn_s_barrier();                           \
  } while (0)

// Fused main kernel — R14 verbatim (proven 62.2 us): NCH=8 (4 blocks/CU),
// fragment-tiled operands (SGPR base + lane*16B), QK transposed, bf16 S-exchange,
// b64 W writes with XOR swizzle, 32 KB LDS, rotated 2-barrier pipeline.
template <bool WS, bool PART>
__global__ __launch_bounds__(512, 4) void attn_fused(
    const float* __restrict__ k, const float* __restrict__ q, const float* __restrict__ v,
    const unsigned short* __restrict__ kbt, const unsigned short* __restrict__ qbt,
    const unsigned short* __restrict__ vtt, void* __restrict__ outp) {
  __shared__ alignas(8)  unsigned short s_pos[NB][8][64][4];   // 16 KB bf16 S^T exchange
  __shared__ alignas(16) unsigned short Wl[NB][BN][BM];        // 16 KB [b][n][m], m swizzled

  const int tid = threadIdx.x;
  const int wv = tid >> 6, l = tid & 63, lr = l & 15, hg = l >> 4;
  const int voff = l << 3;                  // lane offset in elems (16 B)
  const int wg = blockIdx.x;
  const int cid = wg & (NCH - 1);           // == XCD id
  const int nt = wg >> 3;                   // n-tile 0..127
  const int n0 = nt * BN;
  const int it0 = cid * (MM / BM / NCH);
  const int it1 = it0 + (MM / BM / NCH);

  const int bq = wv >> 1, h = wv & 1;          // (batch, m-half) for QK/PV phases
  const int h_s = wv >> 2, fi_s = (wv >> 1) & 1, fj_s = wv & 1;  // softmax slot

  // K fragments (register-cached): rows n0..n0+31 of batch bq, full D
  bf16x8 ka[2][4];
  {
    const unsigned short* kp = WS ? (kbt + rfl(((bq * 256 + nt * 2) * 4) << 9)) : nullptr;
    for (int fn = 0; fn < 2; ++fn)
      for (int kf = 0; kf < 4; ++kf) {
        if (WS) ka[fn][kf] = *(const bf16x8*)(kp + fn * 2048 + kf * 512 + voff);
        else    ka[fn][kf] = pack8(k + ((size_t)bq * NN + n0 + fn * 16 + lr) * DD +
                                   kf * 32 + hg * 8);
      }
  }

  f32x4 acc[2][4];
  for (int fi = 0; fi < 2; ++fi)
    for (int dj = 0; dj < 4; ++dj) acc[fi][dj] = (f32x4){0.f, 0.f, 0.f, 0.f};

  bf16x8 vf[4][2];   // V fragments, live across one barrier
  bf16x8 qf[2][4];   // Q fragments

  auto load_q = [&](int it) {
    if (WS) {
      const unsigned short* qp = qbt + rfl(((bq * 256 + it * 4 + h * 2) * 4) << 9);
      for (int fm = 0; fm < 2; ++fm)
        for (int kf = 0; kf < 4; ++kf)
          qf[fm][kf] = *(const bf16x8*)(qp + fm * 2048 + kf * 512 + voff);
    } else {
      const int m0 = it * BM;
      for (int fm = 0; fm < 2; ++fm)
        for (int kf = 0; kf < 4; ++kf)
          qf[fm][kf] = pack8(q + ((size_t)bq * MM + m0 + h * 32 + fm * 16 + lr) * DD +
                             kf * 32 + hg * 8);
    }
  };

  auto qk_mfma = [&]() {
    f32x4 s[2][2];   // [fm][fn], S^T: row=m, col=n
    for (int fm = 0; fm < 2; ++fm)
      for (int fn = 0; fn < 2; ++fn) s[fm][fn] = (f32x4){0.f, 0.f, 0.f, 0.f};
    __builtin_amdgcn_s_setprio(1);
    for (int kf = 0; kf < 4; ++kf)
      for (int fm = 0; fm < 2; ++fm)
        for (int fn = 0; fn < 2; ++fn)
          s[fm][fn] = __builtin_amdgcn_mfma_f32_16x16x32_bf16(qf[fm][kf], ka[fn][kf],
                                                              s[fm][fn], 0, 0, 0);
    __builtin_amdgcn_s_setprio(0);
    for (int fm = 0; fm < 2; ++fm)
      for (int fn = 0; fn < 2; ++fn) {
        short4 pk;
        pk.x = f2bf(s[fm][fn][0]); pk.y = f2bf(s[fm][fn][1]);
        pk.z = f2bf(s[fm][fn][2]); pk.w = f2bf(s[fm][fn][3]);
        *(short4*)&s_pos[bq][h * 4 + fm * 2 + fn][l][0] = pk;   // b64
      }
  };

  auto issue_v = [&](int it) {
    if (WS) {
      const unsigned short* vp = vtt + rfl((((bq * 8 + h * 4) * 128) + it * 2) << 9);
      for (int dj = 0; dj < 4; ++dj)
        for (int kf = 0; kf < 2; ++kf)
          vf[dj][kf] = *(const bf16x8*)(vp + dj * 65536 + kf * 512 + voff);
    } else {
      const int m0 = it * BM;
      for (int dj = 0; dj < 4; ++dj)
        for (int kf = 0; kf < 2; ++kf) {
          bf16x8 t;
          for (int e = 0; e < 8; ++e)
            t[e] = f2bf(v[((size_t)bq * MM + m0 + kf * 32 + hg * 8 + e) * DD +
                          h * 64 + dj * 16 + lr]);
          vf[dj][kf] = t;
        }
    }
  };

  auto do_sm = [&]() {
    // slot wv: m = h_s*32 + fi_s*16 + hg*4 + qq (4 consecutive), n = fj_s*16 + lr
    float sv[NB][4], w[NB][4];
    for (int bb = 0; bb < NB; ++bb) {
      short4 sp = *(short4*)&s_pos[bb][wv][l][0];
      sv[bb][0] = bf2f((unsigned short)sp.x); sv[bb][1] = bf2f((unsigned short)sp.y);
      sv[bb][2] = bf2f((unsigned short)sp.z); sv[bb][3] = bf2f((unsigned short)sp.w);
    }
    const float L2E = 1.4426950408889634f;
    for (int qq = 0; qq < 4; ++qq) {
      float e0 = fast_exp2(sv[0][qq] * L2E), e1 = fast_exp2(sv[1][qq] * L2E);
      float e2 = fast_exp2(sv[2][qq] * L2E), e3 = fast_exp2(sv[3][qq] * L2E);
      float inv = __builtin_amdgcn_rcpf((e0 + e1) + (e2 + e3)) * L2E;
      float f0 = fast_exp2(e0 * inv), f1 = fast_exp2(e1 * inv);
      float f2v = fast_exp2(e2 * inv), f3 = fast_exp2(e3 * inv);
      float inv2 = __builtin_amdgcn_rcpf((f0 + f1) + (f2v + f3));
      w[0][qq] = f0 * inv2; w[1][qq] = f1 * inv2;
      w[2][qq] = f2v * inv2; w[3][qq] = f3 * inv2;
    }
    const int n_loc = fj_s * 16 + lr;
    const int mchunk = (h_s * 4 + fi_s * 2 + (hg >> 1)) ^ (n_loc & 7);
    const int moff = mchunk * 8 + (hg & 1) * 4;
    for (int bb = 0; bb < NB; ++bb) {
      short4 pk;
      pk.x = f2bf(w[bb][0]); pk.y = f2bf(w[bb][1]);
      pk.z = f2bf(w[bb][2]); pk.w = f2bf(w[bb][3]);
      *(short4*)&Wl[bb][n_loc][moff] = pk;   // b64, 4 consecutive m
    }
  };

  auto do_pv = [&]() {
    bf16x8 wf[2][2];
    for (int fi = 0; fi < 2; ++fi)
      for (int kf = 0; kf < 2; ++kf) {
        const int row = fi * 16 + lr, mo = kf * 32 + hg * 8;
        wf[fi][kf] = *(bf16x8*)&Wl[bq][row][mo ^ ((row & 7) << 3)];
      }
    __builtin_amdgcn_s_setprio(1);
    for (int kf = 0; kf < 2; ++kf)
      for (int fi = 0; fi < 2; ++fi)
        for (int dj = 0; dj < 4; ++dj)
          acc[fi][dj] = __builtin_amdgcn_mfma_f32_16x16x32_bf16(wf[fi][kf], vf[dj][kf],
                                                                acc[fi][dj], 0, 0, 0);
    __builtin_amdgcn_s_setprio(0);
  };

  // ---- rotated pipeline, 2 raw barriers per iteration (R9/R14-proven order) ----
  load_q(it0);
  qk_mfma();
  LGKM0_SBAR();
  for (int t = it0; t < it1; ++t) {
    issue_v(t);              // V loads in flight across the barrier, land before PV
    do_sm();
    LGKM0_SBAR();
    do_pv();                 // vf dies here; load_q after keeps peak liveness low
    if (t + 1 < it1) {
      load_q(t + 1);
      qk_mfma();
    }
    LGKM0_SBAR();
  }

  // ---- epilogue ----
  if (PART) {
    unsigned short* dst = (unsigned short*)outp + (size_t)cid * OUT_ELEMS +
                          rfl((((bq * 256 + nt * 2) * 8 + h * 4)) << 8);
    for (int fi = 0; fi < 2; ++fi)
      for (int dj = 0; dj < 4; ++dj) {
        short4 pk;
        pk.x = f2bf(acc[fi][dj][0]); pk.y = f2bf(acc[fi][dj][1]);
        pk.z = f2bf(acc[fi][dj][2]); pk.w = f2bf(acc[fi][dj][3]);
        *(short4*)(dst + fi * 2048 + dj * 256 + (l << 2)) = pk;
      }
  } else {
    float* dst = (float*)outp;
    for (int fi = 0; fi < 2; ++fi)
      for (int dj = 0; dj < 4; ++dj)
        for (int qq = 0; qq < 4; ++qq)
          atomicAdd(dst + ((size_t)bq * NN + n0 + fi * 16 + hg * 4 + qq) * DD +
                        h * 64 + dj * 16 + lr,
                    acc[fi][dj][qq]);
  }
}

extern "C" void kernel_launch(void* const* d_in, const int* in_sizes, int n_in,
                              void* d_out, int out_size, void* d_ws, size_t ws_size,
                              hipStream_t stream) {
  (void)in_sizes; (void)n_in; (void)out_size;
  const float* k = (const float*)d_in[0];
  const float* q = (const float*)d_in[1];
  const float* v = (const float*)d_in[2];
  float* out = (float*)d_out;

  const size_t elems = (size_t)NB * MM * DD;                    // 2M per tensor
  const size_t need_bf = 3 * elems * sizeof(unsigned short);    // 12 MB
  const size_t need_full = need_bf + NCH * OUT_ELEMS * sizeof(unsigned short);  // 44 MB
  const bool use_ws = (d_ws != nullptr) && (ws_size >= need_bf);
  const bool use_part = (d_ws != nullptr) && (ws_size >= need_full);

  if (use_ws) {
    unsigned short* kbt = (unsigned short*)d_ws;
    unsigned short* qbt = kbt + elems;
    unsigned short* vtt = qbt + elems;
    prep_kernel<<<dim3(NB * 256, 3), 256, 0, stream>>>(k, q, v, kbt, qbt, vtt);
    if (use_part) {
      unsigned short* partials = vtt + elems;
      attn_fused<true, true><<<dim3(NN / BN * NCH), 512, 0, stream>>>(k, q, v, kbt, qbt, vtt,
                                                                      (void*)partials);
      reduce8_frag_kernel<<<2048, 256, 0, stream>>>(partials, out);
    } else {
      zero_out_kernel<<<(NB * NN * DD) / 4 / 256, 256, 0, stream>>>((float4*)out);
      attn_fused<true, false><<<dim3(NN / BN * NCH), 512, 0, stream>>>(k, q, v, kbt, qbt, vtt,
                                                                       (void*)out);
    }
  } else {
    zero_out_kernel<<<(NB * NN * DD) / 4 / 256, 256, 0, stream>>>((float4*)out);
    attn_fused<false, false><<<dim3(NN / BN * NCH), 512, 0, stream>>>(k, q, v, nullptr,
                                                                      nullptr, nullptr,
                                                                      (void*)out);
  }
}

// Round 21
// 74.890 us; speedup vs baseline: 1.1197x; 1.0281x over previous
//
#include <hip/hip_runtime.h>
#include <hip/hip_bf16.h>

#define NB 4
#define NN 4096
#define MM 4096
#define DD 128
#define BN 32
#define BM 64
#define NCH 4   // m-chunks; grid = 128*4 = 512 blocks, XCD-pinned
#define OUT_ELEMS ((size_t)NB * NN * DD)

using f32x4  = __attribute__((ext_vector_type(4))) float;
using bf16x8 = __attribute__((ext_vector_type(8))) short;

__device__ __forceinline__ float fast_exp2(float x) {
  return __builtin_amdgcn_exp2f(x);   // v_exp_f32: D = 2^S0
}

__device__ __forceinline__ int rfl(int x) {  // force wave-uniform -> SGPR
  return __builtin_amdgcn_readfirstlane(x);
}

__device__ __forceinline__ short f2bf(float x) {
  union { __hip_bfloat16 h; short s; } u;
  u.h = __float2bfloat16(x);
  return u.s;
}

__device__ __forceinline__ float bf2f(unsigned short s) {
  union { float f; unsigned u; } u;
  u.u = ((unsigned)s) << 16;
  return u.f;
}

__device__ __forceinline__ bf16x8 pack8(const float* __restrict__ p) {
  float4 a = *(const float4*)p;
  float4 b = *(const float4*)(p + 4);
  bf16x8 r;
  r[0] = f2bf(a.x); r[1] = f2bf(a.y); r[2] = f2bf(a.z); r[3] = f2bf(a.w);
  r[4] = f2bf(b.x); r[5] = f2bf(b.y); r[6] = f2bf(b.z); r[7] = f2bf(b.w);
  return r;
}

__global__ __launch_bounds__(256) void zero_out_kernel(float4* __restrict__ out) {
  out[(size_t)blockIdx.x * 256 + threadIdx.x] = (float4){0.f, 0.f, 0.f, 0.f};
}

// Fused prep: y=0 -> K frag-tiled, y=1 -> Q frag-tiled, y=2 -> V transpose+frag.
__global__ __launch_bounds__(256) void prep_kernel(
    const float* __restrict__ k, const float* __restrict__ q, const float* __restrict__ v,
    unsigned short* __restrict__ kbt, unsigned short* __restrict__ qbt,
    unsigned short* __restrict__ vtt) {
  __shared__ unsigned short t[64][72];   // used by the V-transpose branch only
  if (blockIdx.y < 2) {
    const float* src = blockIdx.y ? q : k;
    unsigned short* dst = blockIdx.y ? qbt : kbt;
    const int blk = blockIdx.x;          // b*256 + rf
    const int b = blk >> 8, rf = blk & 255;
    const int kf = threadIdx.x >> 6, l = threadIdx.x & 63;
    const int lr = l & 15, hg = l >> 4;
    const float* s = src + ((size_t)(b * 4096 + rf * 16 + lr) * DD + kf * 32 + hg * 8);
    *(bf16x8*)(dst + (((size_t)((b * 256 + rf) * 4 + kf)) << 9) + (l << 3)) = pack8(s);
    return;
  }
  if (blockIdx.x >= 512) return;         // V branch needs 512 of the 1024 blocks
  const int b = blockIdx.x >> 7;
  const int rem = blockIdx.x & 127;
  const int d0 = (rem >> 6) * 64, m0 = (rem & 63) * 64;
  const int r = threadIdx.x >> 2, c4 = threadIdx.x & 3;
  const float* src = v + ((size_t)b * MM + m0 + r) * DD + d0 + c4 * 16;
  for (int j = 0; j < 4; ++j) {
    float4 x = *(const float4*)(src + j * 4);
    int dl = c4 * 16 + j * 4;
    t[dl + 0][r] = (unsigned short)f2bf(x.x);
    t[dl + 1][r] = (unsigned short)f2bf(x.y);
    t[dl + 2][r] = (unsigned short)f2bf(x.z);
    t[dl + 3][r] = (unsigned short)f2bf(x.w);
  }
  __syncthreads();
  const int s8 = threadIdx.x >> 5;          // 0..7 sub-tiles (16d x 32m)
  const int dfl = s8 & 3, mtl = s8 >> 2;
  const int t32 = threadIdx.x & 31;
  for (int ll = 0; ll < 2; ++ll) {
    const int l = t32 * 2 + ll;
    const int lr = l & 15, hg = l >> 4;
    bf16x8 val = *(bf16x8*)&t[dfl * 16 + lr][mtl * 32 + hg * 8];
    *(bf16x8*)(vtt + (((size_t)((b * 8 + (d0 >> 4) + dfl) * 128 + (m0 >> 5) + mtl)) << 9) +
               (l << 3)) = val;
  }
}

// Sum NCH fragment-ordered bf16 partials -> f32 out[b][n][d]
__global__ __launch_bounds__(256) void reduce4_frag_kernel(const unsigned short* __restrict__ p,
                                                           float* __restrict__ out) {
  const size_t idx = (size_t)blockIdx.x * 256 + threadIdx.x;  // 524288 total
  float r0 = 0.f, r1 = 0.f, r2 = 0.f, r3 = 0.f;
  for (int c = 0; c < NCH; ++c) {
    ushort4 a = *(const ushort4*)(p + (size_t)c * OUT_ELEMS + idx * 4);
    r0 += bf2f(a.x); r1 += bf2f(a.y); r2 += bf2f(a.z); r3 += bf2f(a.w);
  }
  const int l = (int)(idx & 63);
  const int djg = (int)((idx >> 6) & 7);
  const int nf = (int)((idx >> 9) & 255);
  const int bq = (int)(idx >> 17);
  const int lr = l & 15, hg = l >> 4;
  float* o = out + ((size_t)(bq * 4096 + nf * 16 + hg * 4) * DD + djg * 16 + lr);
  o[0] = r0; o[DD] = r1; o[2 * DD] = r2; o[3 * DD] = r3;
}

// Raw barrier: LDS visibility only — global loads stay in flight (no vmcnt drain).
#define LGKM0_SBAR()                                        \
  do {                                                      \
    asm volatile("s_waitcnt lgkmcnt(0)" ::: "memory");      \
    __builtin_amdgcn_sched_barrier(0);                      \
    __builtin_amdgcn_s_barrier();                           \
  } while (0)

// Fused main kernel — R15 verbatim (proven 63.5 us): SM-split pipeline:
//   I1(t): SM1(t): s_pos -> round-1 exp/rcp -> p regs                  ; BAR
//   I2(t): SM2(t): round-2 -> Wl[t&1] | PV(t-1): Wl[(t-1)&1]+vf(t-1)
//          | load_q(t+1); QK(t+1) -> s_pos | issue_v(t)                ; BAR
template <bool WS, bool PART>
__global__ __launch_bounds__(512, 4) void attn_fused(
    const float* __restrict__ k, const float* __restrict__ q, const float* __restrict__ v,
    const unsigned short* __restrict__ kbt, const unsigned short* __restrict__ qbt,
    const unsigned short* __restrict__ vtt, void* __restrict__ outp) {
  __shared__ alignas(8)  unsigned short s_pos[NB][8][64][4];   // 16 KB bf16 S^T exchange
  __shared__ alignas(16) unsigned short Wl[2][NB][BN][BM];     // 32 KB [b][n][m] dbuf

  const int tid = threadIdx.x;
  const int wv = tid >> 6, l = tid & 63, lr = l & 15, hg = l >> 4;
  const int voff = l << 3;                  // lane offset in elems (16 B)
  const int wg = blockIdx.x;
  const int cid = wg & (NCH - 1);
  const int nt = wg >> 2;                   // n-tile 0..127
  const int n0 = nt * BN;
  const int it0 = cid * (MM / BM / NCH);
  const int it1 = it0 + (MM / BM / NCH);

  const int bq = wv >> 1, h = wv & 1;          // (batch, m-half) for QK/PV phases
  const int h_s = wv >> 2, fi_s = (wv >> 1) & 1, fj_s = wv & 1;  // softmax slot

  // K fragments (register-cached): rows n0..n0+31 of batch bq, full D
  bf16x8 ka[2][4];
  {
    const unsigned short* kp = WS ? (kbt + rfl(((bq * 256 + nt * 2) * 4) << 9)) : nullptr;
    for (int fn = 0; fn < 2; ++fn)
      for (int kf = 0; kf < 4; ++kf) {
        if (WS) ka[fn][kf] = *(const bf16x8*)(kp + fn * 2048 + kf * 512 + voff);
        else    ka[fn][kf] = pack8(k + ((size_t)bq * NN + n0 + fn * 16 + lr) * DD +
                                   kf * 32 + hg * 8);
      }
  }

  f32x4 acc[2][4];
  for (int fi = 0; fi < 2; ++fi)
    for (int dj = 0; dj < 4; ++dj) acc[fi][dj] = (f32x4){0.f, 0.f, 0.f, 0.f};

  bf16x8 vf[4][2];   // V fragments (single generation)
  bf16x8 qf[2][4];   // Q fragments
  float  p[NB][4];   // round-1 softmax results, live across BAR1

  auto load_q = [&](int it) {
    if (WS) {
      const unsigned short* qp = qbt + rfl(((bq * 256 + it * 4 + h * 2) * 4) << 9);
      for (int fm = 0; fm < 2; ++fm)
        for (int kf = 0; kf < 4; ++kf)
          qf[fm][kf] = *(const bf16x8*)(qp + fm * 2048 + kf * 512 + voff);
    } else {
      const int m0 = it * BM;
      for (int fm = 0; fm < 2; ++fm)
        for (int kf = 0; kf < 4; ++kf)
          qf[fm][kf] = pack8(q + ((size_t)bq * MM + m0 + h * 32 + fm * 16 + lr) * DD +
                             kf * 32 + hg * 8);
    }
  };

  auto qk_mfma = [&]() {
    f32x4 s[2][2];   // [fm][fn], S^T: row=m, col=n
    for (int fm = 0; fm < 2; ++fm)
      for (int fn = 0; fn < 2; ++fn) s[fm][fn] = (f32x4){0.f, 0.f, 0.f, 0.f};
    __builtin_amdgcn_s_setprio(1);
    for (int kf = 0; kf < 4; ++kf)
      for (int fm = 0; fm < 2; ++fm)
        for (int fn = 0; fn < 2; ++fn)
          s[fm][fn] = __builtin_amdgcn_mfma_f32_16x16x32_bf16(qf[fm][kf], ka[fn][kf],
                                                              s[fm][fn], 0, 0, 0);
    __builtin_amdgcn_s_setprio(0);
    for (int fm = 0; fm < 2; ++fm)
      for (int fn = 0; fn < 2; ++fn) {
        short4 pk;
        pk.x = f2bf(s[fm][fn][0]); pk.y = f2bf(s[fm][fn][1]);
        pk.z = f2bf(s[fm][fn][2]); pk.w = f2bf(s[fm][fn][3]);
        *(short4*)&s_pos[bq][h * 4 + fm * 2 + fn][l][0] = pk;   // b64
      }
  };

  auto issue_v = [&](int it) {
    if (WS) {
      const unsigned short* vp = vtt + rfl((((bq * 8 + h * 4) * 128) + it * 2) << 9);
      for (int dj = 0; dj < 4; ++dj)
        for (int kf = 0; kf < 2; ++kf)
          vf[dj][kf] = *(const bf16x8*)(vp + dj * 65536 + kf * 512 + voff);
    } else {
      const int m0 = it * BM;
      for (int dj = 0; dj < 4; ++dj)
        for (int kf = 0; kf < 2; ++kf) {
          bf16x8 t;
          for (int e = 0; e < 8; ++e)
            t[e] = f2bf(v[((size_t)bq * MM + m0 + kf * 32 + hg * 8 + e) * DD +
                          h * 64 + dj * 16 + lr]);
          vf[dj][kf] = t;
        }
    }
  };

  // SM round 1: batch-softmax (exp + normalize) -> p regs (scaled by log2 e)
  auto sm_round1 = [&]() {
    const float L2E = 1.4426950408889634f;
    for (int qq = 0; qq < 4; ++qq) {
      float x0, x1, x2, x3;
      {
        short4 s0 = *(short4*)&s_pos[0][wv][l][0];
        short4 s1 = *(short4*)&s_pos[1][wv][l][0];
        short4 s2 = *(short4*)&s_pos[2][wv][l][0];
        short4 s3 = *(short4*)&s_pos[3][wv][l][0];
        const short* a0 = (const short*)&s0;
        const short* a1 = (const short*)&s1;
        const short* a2 = (const short*)&s2;
        const short* a3 = (const short*)&s3;
        x0 = bf2f((unsigned short)a0[qq]); x1 = bf2f((unsigned short)a1[qq]);
        x2 = bf2f((unsigned short)a2[qq]); x3 = bf2f((unsigned short)a3[qq]);
      }
      float e0 = fast_exp2(x0 * L2E), e1 = fast_exp2(x1 * L2E);
      float e2 = fast_exp2(x2 * L2E), e3 = fast_exp2(x3 * L2E);
      float inv = __builtin_amdgcn_rcpf((e0 + e1) + (e2 + e3)) * L2E;
      p[0][qq] = e0 * inv; p[1][qq] = e1 * inv;
      p[2][qq] = e2 * inv; p[3][qq] = e3 * inv;
    }
  };

  // SM round 2: exp of normalized values + normalize -> bf16 W in LDS
  auto sm_round2 = [&](int buf) {
    const int n_loc = fj_s * 16 + lr;
    const int mchunk = (h_s * 4 + fi_s * 2 + (hg >> 1)) ^ (n_loc & 7);
    const int moff = mchunk * 8 + (hg & 1) * 4;
    float w[NB][4];
    for (int qq = 0; qq < 4; ++qq) {
      float f0 = fast_exp2(p[0][qq]), f1 = fast_exp2(p[1][qq]);
      float f2v = fast_exp2(p[2][qq]), f3 = fast_exp2(p[3][qq]);
      float inv2 = __builtin_amdgcn_rcpf((f0 + f1) + (f2v + f3));
      w[0][qq] = f0 * inv2; w[1][qq] = f1 * inv2;
      w[2][qq] = f2v * inv2; w[3][qq] = f3 * inv2;
    }
    for (int bb = 0; bb < NB; ++bb) {
      short4 pk;
      pk.x = f2bf(w[bb][0]); pk.y = f2bf(w[bb][1]);
      pk.z = f2bf(w[bb][2]); pk.w = f2bf(w[bb][3]);
      *(short4*)&Wl[buf][bb][n_loc][moff] = pk;   // b64, 4 consecutive m
    }
  };

  auto do_pv = [&](int buf) {
    bf16x8 wf[2][2];
    for (int fi = 0; fi < 2; ++fi)
      for (int kf = 0; kf < 2; ++kf) {
        const int row = fi * 16 + lr, mo = kf * 32 + hg * 8;
        wf[fi][kf] = *(bf16x8*)&Wl[buf][bq][row][mo ^ ((row & 7) << 3)];
      }
    __builtin_amdgcn_s_setprio(1);
    for (int kf = 0; kf < 2; ++kf)
      for (int fi = 0; fi < 2; ++fi)
        for (int dj = 0; dj < 4; ++dj)
          acc[fi][dj] = __builtin_amdgcn_mfma_f32_16x16x32_bf16(wf[fi][kf], vf[dj][kf],
                                                                acc[fi][dj], 0, 0, 0);
    __builtin_amdgcn_s_setprio(0);
  };

  // ---- SM-split pipeline ----
  load_q(it0);
  qk_mfma();                 // s_pos(it0)
  LGKM0_SBAR();
  for (int t = it0; t < it1; ++t) {
    // I1: round-1 softmax (trans pipe); vf(t-1) loads still landing here
    sm_round1();
    LGKM0_SBAR();
    // I2: round-2 + W-write (VALU/trans) mixed with PV(t-1) + QK(t+1) (MFMA)
    sm_round2(t & 1);
    if (t > it0) do_pv((t - 1) & 1);       // consumes vf(t-1), frees vf regs
    if (t + 1 < it1) {
      load_q(t + 1);
      qk_mfma();                            // writes s_pos(t+1)
    }
    issue_v(t);                             // vf(t): in flight across BAR + I1(t+1)
    LGKM0_SBAR();
  }
  do_pv((it1 - 1) & 1);

  // ---- epilogue ----
  if (PART) {
    unsigned short* dst = (unsigned short*)outp + (size_t)cid * OUT_ELEMS +
                          rfl((((bq * 256 + nt * 2) * 8 + h * 4)) << 8);
    for (int fi = 0; fi < 2; ++fi)
      for (int dj = 0; dj < 4; ++dj) {
        short4 pk;
        pk.x = f2bf(acc[fi][dj][0]); pk.y = f2bf(acc[fi][dj][1]);
        pk.z = f2bf(acc[fi][dj][2]); pk.w = f2bf(acc[fi][dj][3]);
        *(short4*)(dst + fi * 2048 + dj * 256 + (l << 2)) = pk;
      }
  } else {
    float* dst = (float*)outp;
    for (int fi = 0; fi < 2; ++fi)
      for (int dj = 0; dj < 4; ++dj)
        for (int qq = 0; qq < 4; ++qq)
          atomicAdd(dst + ((size_t)bq * NN + n0 + fi * 16 + hg * 4 + qq) * DD +
                        h * 64 + dj * 16 + lr,
                    acc[fi][dj][qq]);
  }
}

extern "C" void kernel_launch(void* const* d_in, const int* in_sizes, int n_in,
                              void* d_out, int out_size, void* d_ws, size_t ws_size,
                              hipStream_t stream) {
  (void)in_sizes; (void)n_in; (void)out_size;
  const float* k = (const float*)d_in[0];
  const float* q = (const float*)d_in[1];
  const float* v = (const float*)d_in[2];
  float* out = (float*)d_out;

  const size_t elems = (size_t)NB * MM * DD;                    // 2M per tensor
  const size_t need_bf = 3 * elems * sizeof(unsigned short);    // 12 MB
  const size_t need_full = need_bf + NCH * OUT_ELEMS * sizeof(unsigned short);  // 28 MB
  const bool use_ws = (d_ws != nullptr) && (ws_size >= need_bf);
  const bool use_part = (d_ws != nullptr) && (ws_size >= need_full);

  if (use_ws) {
    unsigned short* kbt = (unsigned short*)d_ws;
    unsigned short* qbt = kbt + elems;
    unsigned short* vtt = qbt + elems;
    prep_kernel<<<dim3(NB * 256, 3), 256, 0, stream>>>(k, q, v, kbt, qbt, vtt);
    if (use_part) {
      unsigned short* partials = vtt + elems;
      attn_fused<true, true><<<dim3(NN / BN * NCH), 512, 0, stream>>>(k, q, v, kbt, qbt, vtt,
                                                                      (void*)partials);
      reduce4_frag_kernel<<<2048, 256, 0, stream>>>(partials, out);
    } else {
      zero_out_kernel<<<(NB * NN * DD) / 4 / 256, 256, 0, stream>>>((float4*)out);
      attn_fused<true, false><<<dim3(NN / BN * NCH), 512, 0, stream>>>(k, q, v, kbt, qbt, vtt,
                                                                       (void*)out);
    }
  } else {
    zero_out_kernel<<<(NB * NN * DD) / 4 / 256, 256, 0, stream>>>((float4*)out);
    attn_fused<false, false><<<dim3(NN / BN * NCH), 512, 0, stream>>>(k, q, v, nullptr,
                                                                      nullptr, nullptr,
                                                                      (void*)out);
  }
}

// Round 22
// 74.415 us; speedup vs baseline: 1.1269x; 1.0064x over previous
//
#include <hip/hip_runtime.h>
#include <hip/hip_bf16.h>

#define NB 4
#define NN 4096
#define MM 4096
#define DD 128
#define BN 32
#define BM 64
#define NCH 4   // m-chunks; grid = 128*4 = 512 blocks, XCD-pinned
#define OUT_ELEMS ((size_t)NB * NN * DD)

using f32x4  = __attribute__((ext_vector_type(4))) float;
using bf16x8 = __attribute__((ext_vector_type(8))) short;

__device__ __forceinline__ float fast_exp2(float x) {
  return __builtin_amdgcn_exp2f(x);   // v_exp_f32: D = 2^S0
}

__device__ __forceinline__ int rfl(int x) {  // force wave-uniform -> SGPR
  return __builtin_amdgcn_readfirstlane(x);
}

__device__ __forceinline__ short f2bf(float x) {
  union { __hip_bfloat16 h; short s; } u;
  u.h = __float2bfloat16(x);
  return u.s;
}

__device__ __forceinline__ float bf2f(unsigned short s) {
  union { float f; unsigned u; } u;
  u.u = ((unsigned)s) << 16;
  return u.f;
}

__device__ __forceinline__ bf16x8 pack8(const float* __restrict__ p) {
  float4 a = *(const float4*)p;
  float4 b = *(const float4*)(p + 4);
  bf16x8 r;
  r[0] = f2bf(a.x); r[1] = f2bf(a.y); r[2] = f2bf(a.z); r[3] = f2bf(a.w);
  r[4] = f2bf(b.x); r[5] = f2bf(b.y); r[6] = f2bf(b.z); r[7] = f2bf(b.w);
  return r;
}

__global__ __launch_bounds__(256) void zero_out_kernel(float4* __restrict__ out) {
  out[(size_t)blockIdx.x * 256 + threadIdx.x] = (float4){0.f, 0.f, 0.f, 0.f};
}

// Fused prep: y=0 -> K frag-tiled, y=1 -> Q frag-tiled, y=2 -> V transpose+frag.
__global__ __launch_bounds__(256) void prep_kernel(
    const float* __restrict__ k, const float* __restrict__ q, const float* __restrict__ v,
    unsigned short* __restrict__ kbt, unsigned short* __restrict__ qbt,
    unsigned short* __restrict__ vtt) {
  __shared__ unsigned short t[64][72];   // used by the V-transpose branch only
  if (blockIdx.y < 2) {
    const float* src = blockIdx.y ? q : k;
    unsigned short* dst = blockIdx.y ? qbt : kbt;
    const int blk = blockIdx.x;          // b*256 + rf
    const int b = blk >> 8, rf = blk & 255;
    const int kf = threadIdx.x >> 6, l = threadIdx.x & 63;
    const int lr = l & 15, hg = l >> 4;
    const float* s = src + ((size_t)(b * 4096 + rf * 16 + lr) * DD + kf * 32 + hg * 8);
    *(bf16x8*)(dst + (((size_t)((b * 256 + rf) * 4 + kf)) << 9) + (l << 3)) = pack8(s);
    return;
  }
  if (blockIdx.x >= 512) return;         // V branch needs 512 of the 1024 blocks
  const int b = blockIdx.x >> 7;
  const int rem = blockIdx.x & 127;
  const int d0 = (rem >> 6) * 64, m0 = (rem & 63) * 64;
  const int r = threadIdx.x >> 2, c4 = threadIdx.x & 3;
  const float* src = v + ((size_t)b * MM + m0 + r) * DD + d0 + c4 * 16;
  for (int j = 0; j < 4; ++j) {
    float4 x = *(const float4*)(src + j * 4);
    int dl = c4 * 16 + j * 4;
    t[dl + 0][r] = (unsigned short)f2bf(x.x);
    t[dl + 1][r] = (unsigned short)f2bf(x.y);
    t[dl + 2][r] = (unsigned short)f2bf(x.z);
    t[dl + 3][r] = (unsigned short)f2bf(x.w);
  }
  __syncthreads();
  const int s8 = threadIdx.x >> 5;          // 0..7 sub-tiles (16d x 32m)
  const int dfl = s8 & 3, mtl = s8 >> 2;
  const int t32 = threadIdx.x & 31;
  for (int ll = 0; ll < 2; ++ll) {
    const int l = t32 * 2 + ll;
    const int lr = l & 15, hg = l >> 4;
    bf16x8 val = *(bf16x8*)&t[dfl * 16 + lr][mtl * 32 + hg * 8];
    *(bf16x8*)(vtt + (((size_t)((b * 8 + (d0 >> 4) + dfl) * 128 + (m0 >> 5) + mtl)) << 9) +
               (l << 3)) = val;
  }
}

// Sum NCH fragment-ordered bf16 partials -> f32 out[b][n][d]
__global__ __launch_bounds__(256) void reduce4_frag_kernel(const unsigned short* __restrict__ p,
                                                           float* __restrict__ out) {
  const size_t idx = (size_t)blockIdx.x * 256 + threadIdx.x;  // 524288 total
  float r0 = 0.f, r1 = 0.f, r2 = 0.f, r3 = 0.f;
  for (int c = 0; c < NCH; ++c) {
    ushort4 a = *(const ushort4*)(p + (size_t)c * OUT_ELEMS + idx * 4);
    r0 += bf2f(a.x); r1 += bf2f(a.y); r2 += bf2f(a.z); r3 += bf2f(a.w);
  }
  const int l = (int)(idx & 63);
  const int djg = (int)((idx >> 6) & 7);
  const int nf = (int)((idx >> 9) & 255);
  const int bq = (int)(idx >> 17);
  const int lr = l & 15, hg = l >> 4;
  float* o = out + ((size_t)(bq * 4096 + nf * 16 + hg * 4) * DD + djg * 16 + lr);
  o[0] = r0; o[DD] = r1; o[2 * DD] = r2; o[3 * DD] = r3;
}

// Raw barrier: LDS visibility only — global loads stay in flight (no vmcnt drain).
#define LGKM0_SBAR()                                        \
  do {                                                      \
    asm volatile("s_waitcnt lgkmcnt(0)" ::: "memory");      \
    __builtin_amdgcn_sched_barrier(0);                      \
    __builtin_amdgcn_s_barrier();                           \
  } while (0)

// Fused main kernel — ONE barrier per iteration, dual double-buffer:
//   I(t): SM(t){s_pos[t&1] -> Wl[t&1]} | PV(t-1){Wl[(t-1)&1], vf(t-1)}
//         | load_q(t+1); QK(t+1) -> s_pos[(t+1)&1] | issue_v(t) ; BAR
// All producer->consumer pairs separated by exactly one barrier (parity-split).
template <bool WS, bool PART>
__global__ __launch_bounds__(512, 4) void attn_fused(
    const float* __restrict__ k, const float* __restrict__ q, const float* __restrict__ v,
    const unsigned short* __restrict__ kbt, const unsigned short* __restrict__ qbt,
    const unsigned short* __restrict__ vtt, void* __restrict__ outp) {
  __shared__ alignas(8)  unsigned short s_pos[2][NB][8][64][4];  // 32 KB bf16 S^T dbuf
  __shared__ alignas(16) unsigned short Wl[2][NB][BN][BM];       // 32 KB [b][n][m] dbuf

  const int tid = threadIdx.x;
  const int wv = tid >> 6, l = tid & 63, lr = l & 15, hg = l >> 4;
  const int voff = l << 3;                  // lane offset in elems (16 B)
  const int wg = blockIdx.x;
  const int cid = wg & (NCH - 1);
  const int nt = wg >> 2;                   // n-tile 0..127
  const int n0 = nt * BN;
  const int it0 = cid * (MM / BM / NCH);
  const int it1 = it0 + (MM / BM / NCH);

  const int bq = wv >> 1, h = wv & 1;          // (batch, m-half) for QK/PV phases
  const int h_s = wv >> 2, fi_s = (wv >> 1) & 1, fj_s = wv & 1;  // softmax slot

  // K fragments (register-cached): rows n0..n0+31 of batch bq, full D
  bf16x8 ka[2][4];
  {
    const unsigned short* kp = WS ? (kbt + rfl(((bq * 256 + nt * 2) * 4) << 9)) : nullptr;
    for (int fn = 0; fn < 2; ++fn)
      for (int kf = 0; kf < 4; ++kf) {
        if (WS) ka[fn][kf] = *(const bf16x8*)(kp + fn * 2048 + kf * 512 + voff);
        else    ka[fn][kf] = pack8(k + ((size_t)bq * NN + n0 + fn * 16 + lr) * DD +
                                   kf * 32 + hg * 8);
      }
  }

  f32x4 acc[2][4];
  for (int fi = 0; fi < 2; ++fi)
    for (int dj = 0; dj < 4; ++dj) acc[fi][dj] = (f32x4){0.f, 0.f, 0.f, 0.f};

  bf16x8 vf[4][2];   // V fragments (single generation)
  bf16x8 qf[2][4];   // Q fragments

  auto load_q = [&](int it) {
    if (WS) {
      const unsigned short* qp = qbt + rfl(((bq * 256 + it * 4 + h * 2) * 4) << 9);
      for (int fm = 0; fm < 2; ++fm)
        for (int kf = 0; kf < 4; ++kf)
          qf[fm][kf] = *(const bf16x8*)(qp + fm * 2048 + kf * 512 + voff);
    } else {
      const int m0 = it * BM;
      for (int fm = 0; fm < 2; ++fm)
        for (int kf = 0; kf < 4; ++kf)
          qf[fm][kf] = pack8(q + ((size_t)bq * MM + m0 + h * 32 + fm * 16 + lr) * DD +
                             kf * 32 + hg * 8);
    }
  };

  auto qk_mfma = [&](int buf) {
    f32x4 s[2][2];   // [fm][fn], S^T: row=m, col=n
    for (int fm = 0; fm < 2; ++fm)
      for (int fn = 0; fn < 2; ++fn) s[fm][fn] = (f32x4){0.f, 0.f, 0.f, 0.f};
    __builtin_amdgcn_s_setprio(1);
    for (int kf = 0; kf < 4; ++kf)
      for (int fm = 0; fm < 2; ++fm)
        for (int fn = 0; fn < 2; ++fn)
          s[fm][fn] = __builtin_amdgcn_mfma_f32_16x16x32_bf16(qf[fm][kf], ka[fn][kf],
                                                              s[fm][fn], 0, 0, 0);
    __builtin_amdgcn_s_setprio(0);
    for (int fm = 0; fm < 2; ++fm)
      for (int fn = 0; fn < 2; ++fn) {
        short4 pk;
        pk.x = f2bf(s[fm][fn][0]); pk.y = f2bf(s[fm][fn][1]);
        pk.z = f2bf(s[fm][fn][2]); pk.w = f2bf(s[fm][fn][3]);
        *(short4*)&s_pos[buf][bq][h * 4 + fm * 2 + fn][l][0] = pk;   // b64
      }
  };

  auto issue_v = [&](int it) {
    if (WS) {
      const unsigned short* vp = vtt + rfl((((bq * 8 + h * 4) * 128) + it * 2) << 9);
      for (int dj = 0; dj < 4; ++dj)
        for (int kf = 0; kf < 2; ++kf)
          vf[dj][kf] = *(const bf16x8*)(vp + dj * 65536 + kf * 512 + voff);
    } else {
      const int m0 = it * BM;
      for (int dj = 0; dj < 4; ++dj)
        for (int kf = 0; kf < 2; ++kf) {
          bf16x8 t;
          for (int e = 0; e < 8; ++e)
            t[e] = f2bf(v[((size_t)bq * MM + m0 + kf * 32 + hg * 8 + e) * DD +
                          h * 64 + dj * 16 + lr]);
          vf[dj][kf] = t;
        }
    }
  };

  // Full double softmax: s_pos[buf] -> W -> Wl[buf]
  auto do_sm = [&](int buf) {
    float sv[NB][4], w[NB][4];
    for (int bb = 0; bb < NB; ++bb) {
      short4 sp = *(short4*)&s_pos[buf][bb][wv][l][0];
      sv[bb][0] = bf2f((unsigned short)sp.x); sv[bb][1] = bf2f((unsigned short)sp.y);
      sv[bb][2] = bf2f((unsigned short)sp.z); sv[bb][3] = bf2f((unsigned short)sp.w);
    }
    const float L2E = 1.4426950408889634f;
    for (int qq = 0; qq < 4; ++qq) {
      float e0 = fast_exp2(sv[0][qq] * L2E), e1 = fast_exp2(sv[1][qq] * L2E);
      float e2 = fast_exp2(sv[2][qq] * L2E), e3 = fast_exp2(sv[3][qq] * L2E);
      float inv = __builtin_amdgcn_rcpf((e0 + e1) + (e2 + e3)) * L2E;
      float f0 = fast_exp2(e0 * inv), f1 = fast_exp2(e1 * inv);
      float f2v = fast_exp2(e2 * inv), f3 = fast_exp2(e3 * inv);
      float inv2 = __builtin_amdgcn_rcpf((f0 + f1) + (f2v + f3));
      w[0][qq] = f0 * inv2; w[1][qq] = f1 * inv2;
      w[2][qq] = f2v * inv2; w[3][qq] = f3 * inv2;
    }
    const int n_loc = fj_s * 16 + lr;
    const int mchunk = (h_s * 4 + fi_s * 2 + (hg >> 1)) ^ (n_loc & 7);
    const int moff = mchunk * 8 + (hg & 1) * 4;
    for (int bb = 0; bb < NB; ++bb) {
      short4 pk;
      pk.x = f2bf(w[bb][0]); pk.y = f2bf(w[bb][1]);
      pk.z = f2bf(w[bb][2]); pk.w = f2bf(w[bb][3]);
      *(short4*)&Wl[buf][bb][n_loc][moff] = pk;   // b64, 4 consecutive m
    }
  };

  auto do_pv = [&](int buf) {
    bf16x8 wf[2][2];
    for (int fi = 0; fi < 2; ++fi)
      for (int kf = 0; kf < 2; ++kf) {
        const int row = fi * 16 + lr, mo = kf * 32 + hg * 8;
        wf[fi][kf] = *(bf16x8*)&Wl[buf][bq][row][mo ^ ((row & 7) << 3)];
      }
    __builtin_amdgcn_s_setprio(1);
    for (int kf = 0; kf < 2; ++kf)
      for (int fi = 0; fi < 2; ++fi)
        for (int dj = 0; dj < 4; ++dj)
          acc[fi][dj] = __builtin_amdgcn_mfma_f32_16x16x32_bf16(wf[fi][kf], vf[dj][kf],
                                                                acc[fi][dj], 0, 0, 0);
    __builtin_amdgcn_s_setprio(0);
  };

  // ---- ONE barrier per iteration ----
  load_q(it0);
  qk_mfma(it0 & 1);          // s_pos[it0]
  LGKM0_SBAR();
  for (int t = it0; t < it1; ++t) {
    do_sm(t & 1);                          // s_pos[t] -> Wl[t]
    if (t > it0) do_pv((t - 1) & 1);       // Wl[t-1] x vf(t-1); frees vf
    if (t + 1 < it1) {
      load_q(t + 1);
      qk_mfma((t + 1) & 1);                // writes s_pos[t+1]
    }
    __builtin_amdgcn_sched_barrier(0);     // pin: vf loads stay below PV's last use
    issue_v(t);                            // vf(t) in flight across BAR
    LGKM0_SBAR();
  }
  do_pv((it1 - 1) & 1);

  // ---- epilogue ----
  if (PART) {
    unsigned short* dst = (unsigned short*)outp + (size_t)cid * OUT_ELEMS +
                          rfl((((bq * 256 + nt * 2) * 8 + h * 4)) << 8);
    for (int fi = 0; fi < 2; ++fi)
      for (int dj = 0; dj < 4; ++dj) {
        short4 pk;
        pk.x = f2bf(acc[fi][dj][0]); pk.y = f2bf(acc[fi][dj][1]);
        pk.z = f2bf(acc[fi][dj][2]); pk.w = f2bf(acc[fi][dj][3]);
        *(short4*)(dst + fi * 2048 + dj * 256 + (l << 2)) = pk;
      }
  } else {
    float* dst = (float*)outp;
    for (int fi = 0; fi < 2; ++fi)
      for (int dj = 0; dj < 4; ++dj)
        for (int qq = 0; qq < 4; ++qq)
          atomicAdd(dst + ((size_t)bq * NN + n0 + fi * 16 + hg * 4 + qq) * DD +
                        h * 64 + dj * 16 + lr,
                    acc[fi][dj][qq]);
  }
}

extern "C" void kernel_launch(void* const* d_in, const int* in_sizes, int n_in,
                              void* d_out, int out_size, void* d_ws, size_t ws_size,
                              hipStream_t stream) {
  (void)in_sizes; (void)n_in; (void)out_size;
  const float* k = (const float*)d_in[0];
  const float* q = (const float*)d_in[1];
  const float* v = (const float*)d_in[2];
  float* out = (float*)d_out;

  const size_t elems = (size_t)NB * MM * DD;                    // 2M per tensor
  const size_t need_bf = 3 * elems * sizeof(unsigned short);    // 12 MB
  const size_t need_full = need_bf + NCH * OUT_ELEMS * sizeof(unsigned short);  // 28 MB
  const bool use_ws = (d_ws != nullptr) && (ws_size >= need_bf);
  const bool use_part = (d_ws != nullptr) && (ws_size >= need_full);

  if (use_ws) {
    unsigned short* kbt = (unsigned short*)d_ws;
    unsigned short* qbt = kbt + elems;
    unsigned short* vtt = qbt + elems;
    prep_kernel<<<dim3(NB * 256, 3), 256, 0, stream>>>(k, q, v, kbt, qbt, vtt);
    if (use_part) {
      unsigned short* partials = vtt + elems;
      attn_fused<true, true><<<dim3(NN / BN * NCH), 512, 0, stream>>>(k, q, v, kbt, qbt, vtt,
                                                                      (void*)partials);
      reduce4_frag_kernel<<<2048, 256, 0, stream>>>(partials, out);
    } else {
      zero_out_kernel<<<(NB * NN * DD) / 4 / 256, 256, 0, stream>>>((float4*)out);
      attn_fused<true, false><<<dim3(NN / BN * NCH), 512, 0, stream>>>(k, q, v, kbt, qbt, vtt,
                                                                       (void*)out);
    }
  } else {
    zero_out_kernel<<<(NB * NN * DD) / 4 / 256, 256, 0, stream>>>((float4*)out);
    attn_fused<false, false><<<dim3(NN / BN * NCH), 512, 0, stream>>>(k, q, v, nullptr,
                                                                      nullptr, nullptr,
                                                                      (void*)out);
  }
}